// Round 3
// baseline (545.969 us; speedup 1.0000x reference)
//
#include <hip/hip_runtime.h>
#include <math.h>

#define G 2
#define BB 2
#define L 1024
#define DM 256
#define DI 512
#define DS 16
#define DR 16
#define CH 64
#define CL 16              // L / CH
#define RTOT (G*BB*L)      // 4096 rows per layer-step

__device__ __forceinline__ float silu_f(float x) { return x / (1.f + __expf(-x)); }

// ---------------------------------------------------------------------------
// fp32 GEMM: C[r][n] = sum_k A[r*lda+k] * W[lay][n][k]
// 256 threads, microtile (BM/16)x(BN/16). lay = (row0>>11)*2 + step.
// MODE 0: store (atomicAdd if SPLITK>1)
// MODE 2: final out_proj scatter (atomicAdd if SPLITK>1)
// grid = dim3(N/BN, M/BM, SPLITK)
// ---------------------------------------------------------------------------
template<int BM, int BN, int SPLITK, int MODE>
__global__ __launch_bounds__(256) void gemmT(
    const float* __restrict__ A, int lda, int Ktot,
    const float* __restrict__ W, int Nout, int step,
    float* __restrict__ C, int ldc,
    float* __restrict__ outf)
{
    constexpr int TM = BM / 16;
    constexpr int TN = BN / 16;
    __shared__ float As[16][BM + 4];
    __shared__ float Bs[16][BN + 4];

    const int row0 = blockIdx.y * BM;
    const int col0 = blockIdx.x * BN;
    const int g    = row0 >> 11;
    const int lay  = g * 2 + step;
    const float* Wg = W + (size_t)lay * Nout * Ktot;
    const int t  = threadIdx.x;
    const int tx = t & 15, ty = t >> 4;

    const int Kc    = Ktot / SPLITK;
    const int kbase = blockIdx.z * Kc;

    float acc[TM][TN] = {};

    for (int k0 = 0; k0 < Kc; k0 += 16) {
        #pragma unroll
        for (int i = 0; i < BM / 64; i++) {
            int li = t + 256 * i;
            int r  = li >> 2;
            int kc = (li & 3) * 4;
            const float4 a4 = *(const float4*)&A[(size_t)(row0 + r) * lda + kbase + k0 + kc];
            As[kc + 0][r] = a4.x; As[kc + 1][r] = a4.y;
            As[kc + 2][r] = a4.z; As[kc + 3][r] = a4.w;
        }
        #pragma unroll
        for (int i = 0; i < BN / 64; i++) {
            int li = t + 256 * i;
            int r  = li >> 2;
            int kc = (li & 3) * 4;
            float4 w4 = make_float4(0.f, 0.f, 0.f, 0.f);
            if (col0 + r < Nout)
                w4 = *(const float4*)&Wg[(size_t)(col0 + r) * Ktot + kbase + k0 + kc];
            Bs[kc + 0][r] = w4.x; Bs[kc + 1][r] = w4.y;
            Bs[kc + 2][r] = w4.z; Bs[kc + 3][r] = w4.w;
        }
        __syncthreads();

        #pragma unroll
        for (int kk = 0; kk < 16; kk++) {
            float av[TM], bv[TN];
            #pragma unroll
            for (int m = 0; m < TM / 4; m++) {
                float4 a = *(const float4*)&As[kk][m * 64 + ty * 4];
                av[m * 4 + 0] = a.x; av[m * 4 + 1] = a.y;
                av[m * 4 + 2] = a.z; av[m * 4 + 3] = a.w;
            }
            #pragma unroll
            for (int n = 0; n < TN / 4; n++) {
                float4 b = *(const float4*)&Bs[kk][n * 64 + tx * 4];
                bv[n * 4 + 0] = b.x; bv[n * 4 + 1] = b.y;
                bv[n * 4 + 2] = b.z; bv[n * 4 + 3] = b.w;
            }
            #pragma unroll
            for (int i = 0; i < TM; i++)
                #pragma unroll
                for (int j = 0; j < TN; j++) acc[i][j] += av[i] * bv[j];
        }
        __syncthreads();
    }

    #pragma unroll
    for (int i = 0; i < TM; i++) {
        int r = row0 + (i >> 2) * 64 + ty * 4 + (i & 3);
        #pragma unroll
        for (int j = 0; j < TN; j++) {
            int col = col0 + (j >> 2) * 64 + tx * 4 + (j & 3);
            if (col >= Nout) continue;
            float v = acc[i][j];
            if (MODE == 2) {
                int b = (r >> 10) & 1, l = r & 1023;
                size_t dst;
                if (g == 0) dst = ((size_t)(b * 1024 + l) * 512) + col;
                else        dst = ((size_t)(b * 1024 + (1023 - l)) * 512) + 256 + col;
                if (SPLITK > 1) atomicAdd(&outf[dst], v);
                else            outf[dst] = v;
            } else {
                if (SPLITK > 1) atomicAdd(&C[(size_t)r * ldc + col], v);
                else            C[(size_t)r * ldc + col] = v;
            }
        }
    }
}

// ---------------------------------------------------------------------------
// Depthwise causal conv (K=4) + bias + silu on the xc half of XZ.
// ---------------------------------------------------------------------------
__global__ __launch_bounds__(256) void conv_silu(
    const float* __restrict__ XZ, const float* __restrict__ cw,
    const float* __restrict__ cb, float* __restrict__ XC, int step)
{
    int id = blockIdx.x * 256 + threadIdx.x;   // id = r*512 + d
    int d = id & 511;
    int r = id >> 9;
    int g = r >> 11;
    int l = r & 1023;
    int lay = g * 2 + step;
    const float* w = cw + ((size_t)lay * 512 + d) * 4;
    float acc = cb[(size_t)lay * 512 + d];
    #pragma unroll
    for (int k = 0; k < 4; k++) {
        int ls = l - 3 + k;
        if (ls >= 0) acc += w[k] * XZ[(size_t)(r - 3 + k) * 1024 + d];
    }
    XC[id] = silu_f(acc);
}

// ---------------------------------------------------------------------------
// Scan phase A (dt_proj fused): per (gb, chunk, d) compute prod(dA), h_end.
// ---------------------------------------------------------------------------
__global__ __launch_bounds__(512) void scanA(
    const float* __restrict__ XCb, const float* __restrict__ DBLb,
    const float* __restrict__ A_log, const float* __restrict__ Wdt,
    const float* __restrict__ bdt,
    float* __restrict__ Aprod, float* __restrict__ Hend, int step)
{
    __shared__ float dbl[CL][48];
    int blk = blockIdx.x;           // gb*CH + c
    int c  = blk & (CH - 1);
    int gb = blk >> 6;
    int g  = gb >> 1;
    int lay = g * 2 + step;
    int d = threadIdx.x;
    int r0 = gb * L + c * CL;

    for (int id = threadIdx.x; id < CL * 48; id += 512) {
        int rr = id / 48, cc = id - rr * 48;
        dbl[rr][cc] = DBLb[(size_t)(r0 + rr) * 48 + cc];
    }

    float wdt[16];
    const float* wrow = Wdt + ((size_t)lay * DI + d) * DR;
    #pragma unroll
    for (int k = 0; k < 16; k += 4) {
        float4 v = *(const float4*)&wrow[k];
        wdt[k] = v.x; wdt[k + 1] = v.y; wdt[k + 2] = v.z; wdt[k + 3] = v.w;
    }
    float bias = bdt[(size_t)lay * DI + d];

    float a[DS], h[DS], ap[DS];
    const float* al = A_log + ((size_t)lay * DI + d) * DS;
    #pragma unroll
    for (int s = 0; s < DS; s++) { a[s] = -__expf(al[s]); h[s] = 0.f; ap[s] = 1.f; }
    __syncthreads();

    for (int tt = 0; tt < CL; tt++) {
        float dtr = bias;
        #pragma unroll
        for (int k = 0; k < 16; k++) dtr += dbl[tt][k] * wdt[k];
        float dt = (dtr > 20.f) ? dtr : log1pf(__expf(dtr));
        float xc = XCb[(size_t)(r0 + tt) * DI + d];
        float dx = dt * xc;
        #pragma unroll
        for (int s = 0; s < DS; s++) {
            float da = __expf(dt * a[s]);
            h[s] = da * h[s] + dx * dbl[tt][16 + s];
            ap[s] *= da;
        }
    }
    size_t base = ((size_t)(gb * DI + d) * CH + c) * DS;
    #pragma unroll
    for (int s = 0; s < DS; s++) { Aprod[base + s] = ap[s]; Hend[base + s] = h[s]; }
}

// ---------------------------------------------------------------------------
// Combine: serial exclusive scan over the 64 chunks, per (gb,d,s) lane.
// ---------------------------------------------------------------------------
__global__ __launch_bounds__(256) void scanCombine(
    const float* __restrict__ Aprod, float* __restrict__ H)
{
    int idx = blockIdx.x * 256 + threadIdx.x;  // (gb*DI+d)*DS + s
    int s  = idx & 15;
    int gd = idx >> 4;
    size_t base = (size_t)gd * CH * DS + s;
    float h = 0.f;
    for (int c = 0; c < CH; c++) {
        size_t o = base + (size_t)c * DS;
        float aP = Aprod[o];
        float e  = H[o];
        H[o] = h;
        h = aP * h + e;
    }
}

// ---------------------------------------------------------------------------
// Scan phase B (dt_proj fused): replay with h_init, fuse +xc*D, *silu(z).
// ---------------------------------------------------------------------------
__global__ __launch_bounds__(512) void scanB(
    const float* __restrict__ XCb, const float* __restrict__ DBLb,
    const float* __restrict__ XZ, const float* __restrict__ A_log,
    const float* __restrict__ Wdt, const float* __restrict__ bdt,
    const float* __restrict__ Dp, const float* __restrict__ Hinit,
    float* __restrict__ Yb, int step)
{
    __shared__ float dbl[CL][48];
    int blk = blockIdx.x;
    int c  = blk & (CH - 1);
    int gb = blk >> 6;
    int g  = gb >> 1;
    int lay = g * 2 + step;
    int d = threadIdx.x;
    int r0 = gb * L + c * CL;

    for (int id = threadIdx.x; id < CL * 48; id += 512) {
        int rr = id / 48, cc = id - rr * 48;
        dbl[rr][cc] = DBLb[(size_t)(r0 + rr) * 48 + cc];
    }

    float wdt[16];
    const float* wrow = Wdt + ((size_t)lay * DI + d) * DR;
    #pragma unroll
    for (int k = 0; k < 16; k += 4) {
        float4 v = *(const float4*)&wrow[k];
        wdt[k] = v.x; wdt[k + 1] = v.y; wdt[k + 2] = v.z; wdt[k + 3] = v.w;
    }
    float bias = bdt[(size_t)lay * DI + d];

    float a[DS], h[DS];
    const float* al = A_log + ((size_t)lay * DI + d) * DS;
    size_t base = ((size_t)(gb * DI + d) * CH + c) * DS;
    #pragma unroll
    for (int s = 0; s < DS; s++) { a[s] = -__expf(al[s]); h[s] = Hinit[base + s]; }
    float Dv = Dp[(size_t)lay * DI + d];
    __syncthreads();

    for (int tt = 0; tt < CL; tt++) {
        int r = r0 + tt;
        float dtr = bias;
        #pragma unroll
        for (int k = 0; k < 16; k++) dtr += dbl[tt][k] * wdt[k];
        float dt = (dtr > 20.f) ? dtr : log1pf(__expf(dtr));
        float xc = XCb[(size_t)r * DI + d];
        float dx = dt * xc;
        float y = 0.f;
        #pragma unroll
        for (int s = 0; s < DS; s++) {
            float da = __expf(dt * a[s]);
            h[s] = da * h[s] + dx * dbl[tt][16 + s];
            y += h[s] * dbl[tt][32 + s];
        }
        y += xc * Dv;
        float z = XZ[(size_t)r * 1024 + 512 + d];
        y *= silu_f(z);
        Yb[(size_t)r * DI + d] = y;
    }
}

// ---------------------------------------------------------------------------
// Build the G=2 batched input: chain 0 = x, chain 1 = x time-reversed.
// ---------------------------------------------------------------------------
__global__ __launch_bounds__(256) void initX(
    const float* __restrict__ x, float* __restrict__ X0)
{
    int id = blockIdx.x * 256 + threadIdx.x;
    int m = id & 255;
    int r = id >> 8;
    int g = r >> 11, b = (r >> 10) & 1, l = r & 1023;
    int sl = g ? (1023 - l) : l;
    X0[id] = x[(size_t)(b * 1024 + sl) * 256 + m];
}

extern "C" void kernel_launch(void* const* d_in, const int* in_sizes, int n_in,
                              void* d_out, int out_size, void* d_ws, size_t ws_size,
                              hipStream_t stream)
{
    const float* x        = (const float*)d_in[0];
    const float* in_proj  = (const float*)d_in[1];
    const float* conv_w   = (const float*)d_in[2];
    const float* conv_b   = (const float*)d_in[3];
    const float* x_proj   = (const float*)d_in[4];
    const float* dt_proj  = (const float*)d_in[5];
    const float* dt_bias  = (const float*)d_in[6];
    const float* A_log    = (const float*)d_in[7];
    const float* Dp       = (const float*)d_in[8];
    const float* out_proj = (const float*)d_in[9];
    float* out = (float*)d_out;

    float* w = (float*)d_ws;
    size_t o = 0;
    float* X0    = w + o; o += (size_t)RTOT * DM;
    float* X1    = w + o; o += (size_t)RTOT * DM;
    float* XZ    = w + o; o += (size_t)RTOT * 1024;
    float* XCb   = w + o; o += (size_t)RTOT * DI;
    float* DBLb  = w + o; o += (size_t)RTOT * 48;
    float* Yb    = w + o; o += (size_t)RTOT * DI;
    float* Aprod = w + o; o += (size_t)G * BB * DI * CH * DS;
    float* Hend  = w + o; o += (size_t)G * BB * DI * CH * DS;
    (void)ws_size; (void)in_sizes; (void)n_in; (void)out_size;

    initX<<<RTOT * DM / 256, 256, 0, stream>>>(x, X0);
    hipMemsetAsync(X1, 0, (size_t)RTOT * DM * 4, stream);          // split-K target
    hipMemsetAsync(out, 0, (size_t)out_size * 4, stream);          // split-K target

    for (int step = 0; step < 2; step++) {
        const float* Xin = step ? X1 : X0;
        // in_proj: 4096x1024, K=256. 64x128 tiles -> 512 blocks (2/CU).
        gemmT<64, 128, 1, 0><<<dim3(8, 64, 1), 256, 0, stream>>>(
            Xin, DM, DM, in_proj, 2 * DI, step, XZ, 1024, nullptr);
        conv_silu<<<RTOT * DI / 256, 256, 0, stream>>>(XZ, conv_w, conv_b, XCb, step);
        // x_proj: 4096x48, K=512 split 16 -> 512 blocks.
        hipMemsetAsync(DBLb, 0, (size_t)RTOT * 48 * 4, stream);
        gemmT<128, 64, 16, 0><<<dim3(1, 32, 16), 256, 0, stream>>>(
            XCb, DI, DI, x_proj, 48, step, DBLb, 48, nullptr);
        // fused dt_proj + chunked scan
        scanA<<<G * BB * CH, 512, 0, stream>>>(
            XCb, DBLb, A_log, dt_proj, dt_bias, Aprod, Hend, step);
        scanCombine<<<(G * BB * DI * DS) / 256, 256, 0, stream>>>(Aprod, Hend);
        scanB<<<G * BB * CH, 512, 0, stream>>>(
            XCb, DBLb, XZ, A_log, dt_proj, dt_bias, Dp, Hend, Yb, step);
        // out_proj: 4096x256, K=512 split 4 -> 512 blocks.
        if (step == 0)
            gemmT<64, 128, 4, 0><<<dim3(2, 64, 4), 256, 0, stream>>>(
                Yb, DI, DI, out_proj, DM, step, X1, DM, nullptr);
        else
            gemmT<64, 128, 4, 2><<<dim3(2, 64, 4), 256, 0, stream>>>(
                Yb, DI, DI, out_proj, DM, step, nullptr, 0, out);
    }
}

// Round 4
// 381.167 us; speedup vs baseline: 1.4324x; 1.4324x over previous
//
#include <hip/hip_runtime.h>
#include <math.h>

#define G 2
#define BB 2
#define L 1024
#define DM 256
#define DI 512
#define DS 16
#define DR 16
#define CH 64
#define CL 16              // L / CH
#define RTOT (G*BB*L)      // 4096 rows per layer-step

__device__ __forceinline__ float silu_f(float x) { return x / (1.f + __expf(-x)); }

// ---------------------------------------------------------------------------
// Pipelined fp32 GEMM: C[z][r][n] = sum_k A[r*lda+k] * W[lay][n][k]
// Double-buffered LDS, one barrier per K-tile. No atomics: each split-K
// block writes its own partial slab (C + z*partStride).
// SUMA: A := A + A[AsumOff] (fuses the previous split-2 combine).
// ---------------------------------------------------------------------------
template<int BM, int BN, int SPLITK, int SUMA>
__global__ __launch_bounds__(256) void gemmP(
    const float* __restrict__ A, size_t AsumOff, int lda, int Ktot,
    const float* __restrict__ W, int Nout, int step,
    float* __restrict__ C, int ldc, size_t partStride)
{
    constexpr int TM = BM / 16;
    constexpr int TN = BN / 16;
    __shared__ float As[2][16][BM + 4];
    __shared__ float Bs[2][16][BN + 4];

    const int row0 = blockIdx.y * BM;
    const int col0 = blockIdx.x * BN;
    const int g    = row0 >> 11;
    const int lay  = g * 2 + step;
    const float* Wg = W + (size_t)lay * Nout * Ktot;
    const int t  = threadIdx.x;
    const int tx = t & 15, ty = t >> 4;
    const int Kc    = Ktot / SPLITK;
    const int kbase = blockIdx.z * Kc;
    const int NT    = Kc / 16;

    float4 ra[BM / 64], ra2[BM / 64], rb[BN / 64];

    auto loadT = [&](int kt) {
        const int kb = kbase + kt * 16;
        #pragma unroll
        for (int i = 0; i < BM / 64; i++) {
            int li = t + 256 * i, r = li >> 2, kc = (li & 3) * 4;
            ra[i] = *(const float4*)&A[(size_t)(row0 + r) * lda + kb + kc];
            if (SUMA)
                ra2[i] = *(const float4*)&A[AsumOff + (size_t)(row0 + r) * lda + kb + kc];
        }
        #pragma unroll
        for (int i = 0; i < BN / 64; i++) {
            int li = t + 256 * i, r = li >> 2, kc = (li & 3) * 4;
            rb[i] = (col0 + r < Nout)
                  ? *(const float4*)&Wg[(size_t)(col0 + r) * Ktot + kb + kc]
                  : make_float4(0.f, 0.f, 0.f, 0.f);
        }
    };
    auto storeT = [&](int buf) {
        #pragma unroll
        for (int i = 0; i < BM / 64; i++) {
            int li = t + 256 * i, r = li >> 2, kc = (li & 3) * 4;
            float4 v = ra[i];
            if (SUMA) { v.x += ra2[i].x; v.y += ra2[i].y; v.z += ra2[i].z; v.w += ra2[i].w; }
            As[buf][kc + 0][r] = v.x; As[buf][kc + 1][r] = v.y;
            As[buf][kc + 2][r] = v.z; As[buf][kc + 3][r] = v.w;
        }
        #pragma unroll
        for (int i = 0; i < BN / 64; i++) {
            int li = t + 256 * i, r = li >> 2, kc = (li & 3) * 4;
            float4 v = rb[i];
            Bs[buf][kc + 0][r] = v.x; Bs[buf][kc + 1][r] = v.y;
            Bs[buf][kc + 2][r] = v.z; Bs[buf][kc + 3][r] = v.w;
        }
    };

    float acc[TM][TN] = {};
    loadT(0); storeT(0); __syncthreads();

    for (int kt = 0; kt < NT; kt++) {
        const int cur = kt & 1;
        if (kt + 1 < NT) loadT(kt + 1);
        #pragma unroll
        for (int kk = 0; kk < 16; kk++) {
            float av[TM], bv[TN];
            #pragma unroll
            for (int m = 0; m < TM / 4; m++) {
                float4 a = *(const float4*)&As[cur][kk][m * 64 + ty * 4];
                av[m * 4 + 0] = a.x; av[m * 4 + 1] = a.y;
                av[m * 4 + 2] = a.z; av[m * 4 + 3] = a.w;
            }
            #pragma unroll
            for (int n = 0; n < TN / 4; n++) {
                float4 b = *(const float4*)&Bs[cur][kk][n * 64 + tx * 4];
                bv[n * 4 + 0] = b.x; bv[n * 4 + 1] = b.y;
                bv[n * 4 + 2] = b.z; bv[n * 4 + 3] = b.w;
            }
            #pragma unroll
            for (int i = 0; i < TM; i++)
                #pragma unroll
                for (int j = 0; j < TN; j++) acc[i][j] += av[i] * bv[j];
        }
        if (kt + 1 < NT) storeT(cur ^ 1);
        __syncthreads();
    }

    float* Cz = C + (size_t)blockIdx.z * partStride;
    #pragma unroll
    for (int i = 0; i < TM; i++) {
        int r = row0 + (i >> 2) * 64 + ty * 4 + (i & 3);
        #pragma unroll
        for (int jq = 0; jq < TN / 4; jq++) {
            int col = col0 + jq * 64 + tx * 4;
            if (col >= Nout) continue;
            float4 v = make_float4(acc[i][jq * 4 + 0], acc[i][jq * 4 + 1],
                                   acc[i][jq * 4 + 2], acc[i][jq * 4 + 3]);
            *(float4*)&Cz[(size_t)r * ldc + col] = v;
        }
    }
}

// ---------------------------------------------------------------------------
// Combine the 8 x_proj split-K partials into DBLb.
// ---------------------------------------------------------------------------
__global__ __launch_bounds__(256) void combineDBL(
    const float* __restrict__ P, float* __restrict__ DBLb)
{
    int idx = blockIdx.x * 256 + threadIdx.x;   // 4096*48
    float v = 0.f;
    #pragma unroll
    for (int s = 0; s < 8; s++) v += P[(size_t)s * (RTOT * 48) + idx];
    DBLb[idx] = v;
}

// ---------------------------------------------------------------------------
// Final out_proj combine + time-reversal scatter into d_out.
// ---------------------------------------------------------------------------
__global__ __launch_bounds__(256) void combineOut(
    const float* __restrict__ P, float* __restrict__ out)
{
    int idx = blockIdx.x * 256 + threadIdx.x;   // 2*1024*512
    int c  = idx & 511;
    int bl = idx >> 9;
    int b = bl >> 10, l = bl & 1023;
    int r, col;
    if (c < 256) { r = b * 1024 + l;                 col = c; }
    else         { r = 2048 + b * 1024 + (1023 - l); col = c - 256; }
    size_t o = (size_t)r * 256 + col;
    out[idx] = P[o] + P[(size_t)RTOT * 256 + o];
}

// ---------------------------------------------------------------------------
// Depthwise causal conv (K=4) + bias + silu on the xc half of XZ.
// ---------------------------------------------------------------------------
__global__ __launch_bounds__(256) void conv_silu(
    const float* __restrict__ XZ, const float* __restrict__ cw,
    const float* __restrict__ cb, float* __restrict__ XC, int step)
{
    int id = blockIdx.x * 256 + threadIdx.x;   // id = r*512 + d
    int d = id & 511;
    int r = id >> 9;
    int g = r >> 11;
    int l = r & 1023;
    int lay = g * 2 + step;
    const float* w = cw + ((size_t)lay * 512 + d) * 4;
    float acc = cb[(size_t)lay * 512 + d];
    #pragma unroll
    for (int k = 0; k < 4; k++) {
        int ls = l - 3 + k;
        if (ls >= 0) acc += w[k] * XZ[(size_t)(r - 3 + k) * 1024 + d];
    }
    XC[id] = silu_f(acc);
}

// ---------------------------------------------------------------------------
// Scan phase A (dt_proj fused): per (gb, chunk, d) compute prod(dA), h_end.
// ---------------------------------------------------------------------------
__global__ __launch_bounds__(512) void scanA(
    const float* __restrict__ XCb, const float* __restrict__ DBLb,
    const float* __restrict__ A_log, const float* __restrict__ Wdt,
    const float* __restrict__ bdt,
    float* __restrict__ Aprod, float* __restrict__ Hend, int step)
{
    __shared__ float dbl[CL][48];
    int blk = blockIdx.x;           // gb*CH + c
    int c  = blk & (CH - 1);
    int gb = blk >> 6;
    int g  = gb >> 1;
    int lay = g * 2 + step;
    int d = threadIdx.x;
    int r0 = gb * L + c * CL;

    for (int id = threadIdx.x; id < CL * 48; id += 512) {
        int rr = id / 48, cc = id - rr * 48;
        dbl[rr][cc] = DBLb[(size_t)(r0 + rr) * 48 + cc];
    }

    float wdt[16];
    const float* wrow = Wdt + ((size_t)lay * DI + d) * DR;
    #pragma unroll
    for (int k = 0; k < 16; k += 4) {
        float4 v = *(const float4*)&wrow[k];
        wdt[k] = v.x; wdt[k + 1] = v.y; wdt[k + 2] = v.z; wdt[k + 3] = v.w;
    }
    float bias = bdt[(size_t)lay * DI + d];

    float a[DS], h[DS], ap[DS];
    const float* al = A_log + ((size_t)lay * DI + d) * DS;
    #pragma unroll
    for (int s = 0; s < DS; s++) { a[s] = -__expf(al[s]); h[s] = 0.f; ap[s] = 1.f; }
    __syncthreads();

    for (int tt = 0; tt < CL; tt++) {
        float dtr = bias;
        #pragma unroll
        for (int k = 0; k < 16; k++) dtr += dbl[tt][k] * wdt[k];
        float dt = (dtr > 20.f) ? dtr : log1pf(__expf(dtr));
        float xc = XCb[(size_t)(r0 + tt) * DI + d];
        float dx = dt * xc;
        #pragma unroll
        for (int s = 0; s < DS; s++) {
            float da = __expf(dt * a[s]);
            h[s] = da * h[s] + dx * dbl[tt][16 + s];
            ap[s] *= da;
        }
    }
    size_t base = ((size_t)(gb * DI + d) * CH + c) * DS;
    #pragma unroll
    for (int s = 0; s < DS; s++) { Aprod[base + s] = ap[s]; Hend[base + s] = h[s]; }
}

// ---------------------------------------------------------------------------
// Combine: serial exclusive scan over the 64 chunks, per (gb,d,s) lane.
// ---------------------------------------------------------------------------
__global__ __launch_bounds__(256) void scanCombine(
    const float* __restrict__ Aprod, float* __restrict__ H)
{
    int idx = blockIdx.x * 256 + threadIdx.x;  // (gb*DI+d)*DS + s
    int s  = idx & 15;
    int gd = idx >> 4;
    size_t base = (size_t)gd * CH * DS + s;
    float h = 0.f;
    for (int c = 0; c < CH; c++) {
        size_t o = base + (size_t)c * DS;
        float aP = Aprod[o];
        float e  = H[o];
        H[o] = h;
        h = aP * h + e;
    }
}

// ---------------------------------------------------------------------------
// Scan phase B (dt_proj fused): replay with h_init, fuse +xc*D, *silu(z).
// ---------------------------------------------------------------------------
__global__ __launch_bounds__(512) void scanB(
    const float* __restrict__ XCb, const float* __restrict__ DBLb,
    const float* __restrict__ XZ, const float* __restrict__ A_log,
    const float* __restrict__ Wdt, const float* __restrict__ bdt,
    const float* __restrict__ Dp, const float* __restrict__ Hinit,
    float* __restrict__ Yb, int step)
{
    __shared__ float dbl[CL][48];
    int blk = blockIdx.x;
    int c  = blk & (CH - 1);
    int gb = blk >> 6;
    int g  = gb >> 1;
    int lay = g * 2 + step;
    int d = threadIdx.x;
    int r0 = gb * L + c * CL;

    for (int id = threadIdx.x; id < CL * 48; id += 512) {
        int rr = id / 48, cc = id - rr * 48;
        dbl[rr][cc] = DBLb[(size_t)(r0 + rr) * 48 + cc];
    }

    float wdt[16];
    const float* wrow = Wdt + ((size_t)lay * DI + d) * DR;
    #pragma unroll
    for (int k = 0; k < 16; k += 4) {
        float4 v = *(const float4*)&wrow[k];
        wdt[k] = v.x; wdt[k + 1] = v.y; wdt[k + 2] = v.z; wdt[k + 3] = v.w;
    }
    float bias = bdt[(size_t)lay * DI + d];

    float a[DS], h[DS];
    const float* al = A_log + ((size_t)lay * DI + d) * DS;
    size_t base = ((size_t)(gb * DI + d) * CH + c) * DS;
    #pragma unroll
    for (int s = 0; s < DS; s++) { a[s] = -__expf(al[s]); h[s] = Hinit[base + s]; }
    float Dv = Dp[(size_t)lay * DI + d];
    __syncthreads();

    for (int tt = 0; tt < CL; tt++) {
        int r = r0 + tt;
        float dtr = bias;
        #pragma unroll
        for (int k = 0; k < 16; k++) dtr += dbl[tt][k] * wdt[k];
        float dt = (dtr > 20.f) ? dtr : log1pf(__expf(dtr));
        float xc = XCb[(size_t)r * DI + d];
        float dx = dt * xc;
        float y = 0.f;
        #pragma unroll
        for (int s = 0; s < DS; s++) {
            float da = __expf(dt * a[s]);
            h[s] = da * h[s] + dx * dbl[tt][16 + s];
            y += h[s] * dbl[tt][32 + s];
        }
        y += xc * Dv;
        float z = XZ[(size_t)r * 1024 + 512 + d];
        y *= silu_f(z);
        Yb[(size_t)r * DI + d] = y;
    }
}

// ---------------------------------------------------------------------------
// Build the G=2 batched input: chain 0 = x, chain 1 = x time-reversed.
// ---------------------------------------------------------------------------
__global__ __launch_bounds__(256) void initX(
    const float* __restrict__ x, float* __restrict__ X0)
{
    int id = blockIdx.x * 256 + threadIdx.x;
    int m = id & 255;
    int r = id >> 8;
    int g = r >> 11, b = (r >> 10) & 1, l = r & 1023;
    int sl = g ? (1023 - l) : l;
    X0[id] = x[(size_t)(b * 1024 + sl) * 256 + m];
}

extern "C" void kernel_launch(void* const* d_in, const int* in_sizes, int n_in,
                              void* d_out, int out_size, void* d_ws, size_t ws_size,
                              hipStream_t stream)
{
    const float* x        = (const float*)d_in[0];
    const float* in_proj  = (const float*)d_in[1];
    const float* conv_w   = (const float*)d_in[2];
    const float* conv_b   = (const float*)d_in[3];
    const float* x_proj   = (const float*)d_in[4];
    const float* dt_proj  = (const float*)d_in[5];
    const float* dt_bias  = (const float*)d_in[6];
    const float* A_log    = (const float*)d_in[7];
    const float* Dp       = (const float*)d_in[8];
    const float* out_proj = (const float*)d_in[9];
    float* out = (float*)d_out;

    float* w = (float*)d_ws;
    size_t o = 0;
    float* X0    = w + o; o += (size_t)RTOT * DM;              // 1.0M
    float* XZ    = w + o; o += (size_t)RTOT * 1024;            // 4.2M
    float* XCb   = w + o; o += (size_t)RTOT * DI;              // 2.1M
    float* DBLb  = w + o; o += (size_t)RTOT * 48;              // 0.2M
    float* Yb    = w + o; o += (size_t)RTOT * DI;              // 2.1M (aliases Pdbl)
    float* Pdbl  = Yb;                                         // 8*RTOT*48 = 1.6M < 2.1M
    float* Aprod = w + o; o += (size_t)G * BB * DI * CH * DS;  // 0.5M
    float* Hend  = w + o; o += (size_t)G * BB * DI * CH * DS;  // 0.5M
    float* Pout  = w + o; o += (size_t)2 * RTOT * DM;          // 2.1M
    (void)ws_size; (void)in_sizes; (void)n_in; (void)out_size;

    initX<<<RTOT * DM / 256, 256, 0, stream>>>(x, X0);

    for (int step = 0; step < 2; step++) {
        // in_proj: 4096x1024, K=256. step1 fuses Pout[0]+Pout[1] as input.
        if (step == 0)
            gemmP<128, 128, 1, 0><<<dim3(8, 32, 1), 256, 0, stream>>>(
                X0, 0, DM, DM, in_proj, 2 * DI, 0, XZ, 1024, 0);
        else
            gemmP<128, 128, 1, 1><<<dim3(8, 32, 1), 256, 0, stream>>>(
                Pout, (size_t)RTOT * DM, DM, DM, in_proj, 2 * DI, 1, XZ, 1024, 0);
        conv_silu<<<RTOT * DI / 256, 256, 0, stream>>>(XZ, conv_w, conv_b, XCb, step);
        // x_proj: 4096x48, K=512 split-8, private partials (no atomics).
        gemmP<128, 64, 8, 0><<<dim3(1, 32, 8), 256, 0, stream>>>(
            XCb, 0, DI, DI, x_proj, 48, step, Pdbl, 48, (size_t)RTOT * 48);
        combineDBL<<<RTOT * 48 / 256, 256, 0, stream>>>(Pdbl, DBLb);
        // fused dt_proj + chunked scan
        scanA<<<G * BB * CH, 512, 0, stream>>>(
            XCb, DBLb, A_log, dt_proj, dt_bias, Aprod, Hend, step);
        scanCombine<<<(G * BB * DI * DS) / 256, 256, 0, stream>>>(Aprod, Hend);
        scanB<<<G * BB * CH, 512, 0, stream>>>(
            XCb, DBLb, XZ, A_log, dt_proj, dt_bias, Dp, Hend, Yb, step);
        // out_proj: 4096x256, K=512 split-2, private partials.
        gemmP<64, 128, 2, 0><<<dim3(2, 64, 2), 256, 0, stream>>>(
            Yb, 0, DI, DI, out_proj, DM, step, Pout, DM, (size_t)RTOT * DM);
    }
    combineOut<<<(2 * 1024 * 512) / 256, 256, 0, stream>>>(Pout, out);
}

// Round 5
// 333.924 us; speedup vs baseline: 1.6350x; 1.1415x over previous
//
#include <hip/hip_runtime.h>
#include <math.h>

#define G 2
#define BB 2
#define L 1024
#define DM 256
#define DI 512
#define DS 16
#define DR 16
#define CH 64
#define CL 16              // L / CH
#define RTOT (G*BB*L)      // 4096 rows per layer-step
#define SKX 8              // x_proj split-K factor

__device__ __forceinline__ float silu_f(float x) { return x / (1.f + __expf(-x)); }

// ---------------------------------------------------------------------------
// fp32 GEMM, 64x64 tile, 4x4 microtile, 256 threads, single LDS buffer with
// register prefetch. Low VGPR (target ~8 waves/SIMD).
// C[z][r][n] = sum_k A[r][k] * W[lay][n][k]; lay = (row0>>11)*2 + step.
// AMAP 0: A direct. AMAP 1: A = x with g-dependent time reversal (step0
// in_proj). AMAP 2: A = slab0 + slab1 (fuses out_proj split-2 combine into
// step1 in_proj). Split-K blocks write private slabs (z*partStride).
// ---------------------------------------------------------------------------
template<int SPLITK, int AMAP>
__global__ __launch_bounds__(256) void gemm64(
    const float* __restrict__ A, size_t slabOff, int lda, int Ktot,
    const float* __restrict__ W, int Nout, int step,
    float* __restrict__ C, int ldc, size_t partStride)
{
    __shared__ float As[16][68];
    __shared__ float Bs[16][68];

    const int row0 = blockIdx.y * 64;
    const int col0 = blockIdx.x * 64;
    const int g    = row0 >> 11;
    const int lay  = g * 2 + step;
    const float* Wg = W + (size_t)lay * Nout * Ktot;
    const int t  = threadIdx.x;
    const int tx = t & 15, ty = t >> 4;
    const int Kc    = Ktot / SPLITK;
    const int kbase = blockIdx.z * Kc;
    const int NT    = Kc / 16;

    // per-thread staging indices (one float4 of A, one of B per K-tile)
    const int sr = t >> 2;            // 0..63
    const int sk = (t & 3) * 4;       // 0,4,8,12

    // A source row (resolve AMAP once)
    size_t arow;
    if (AMAP == 1) {
        int gr = row0 + sr;
        int gg = gr >> 11, b = (gr >> 10) & 1, l = gr & 1023;
        int sl = gg ? (1023 - l) : l;
        arow = (size_t)(b * 1024 + sl);
    } else {
        arow = (size_t)(row0 + sr);
    }
    const bool bok = (col0 + sr < Nout);

    float4 pa, pb;
    auto loadT = [&](int kt) {
        const int kb = kbase + kt * 16 + sk;
        pa = *(const float4*)&A[arow * lda + kb];
        if (AMAP == 2) {
            float4 q = *(const float4*)&A[slabOff + arow * lda + kb];
            pa.x += q.x; pa.y += q.y; pa.z += q.z; pa.w += q.w;
        }
        pb = bok ? *(const float4*)&Wg[(size_t)(col0 + sr) * Ktot + kb]
                 : make_float4(0.f, 0.f, 0.f, 0.f);
    };

    float acc[4][4] = {};
    loadT(0);

    for (int kt = 0; kt < NT; kt++) {
        As[sk + 0][sr] = pa.x; As[sk + 1][sr] = pa.y;
        As[sk + 2][sr] = pa.z; As[sk + 3][sr] = pa.w;
        Bs[sk + 0][sr] = pb.x; Bs[sk + 1][sr] = pb.y;
        Bs[sk + 2][sr] = pb.z; Bs[sk + 3][sr] = pb.w;
        __syncthreads();
        if (kt + 1 < NT) loadT(kt + 1);   // prefetch under compute
        #pragma unroll
        for (int kk = 0; kk < 16; kk++) {
            float4 a = *(const float4*)&As[kk][ty * 4];
            float4 b = *(const float4*)&Bs[kk][tx * 4];
            float av[4] = {a.x, a.y, a.z, a.w};
            float bv[4] = {b.x, b.y, b.z, b.w};
            #pragma unroll
            for (int i = 0; i < 4; i++)
                #pragma unroll
                for (int j = 0; j < 4; j++) acc[i][j] += av[i] * bv[j];
        }
        __syncthreads();
    }

    float* Cz = C + (size_t)blockIdx.z * partStride;
    const int col = col0 + tx * 4;
    if (col < Nout) {
        #pragma unroll
        for (int i = 0; i < 4; i++) {
            int r = row0 + ty * 4 + i;
            *(float4*)&Cz[(size_t)r * ldc + col] =
                make_float4(acc[i][0], acc[i][1], acc[i][2], acc[i][3]);
        }
    }
}

// ---------------------------------------------------------------------------
// Final out_proj combine (2 slabs) + time-reversal scatter into d_out.
// ---------------------------------------------------------------------------
__global__ __launch_bounds__(256) void combineOut(
    const float* __restrict__ P, float* __restrict__ out)
{
    int idx = blockIdx.x * 256 + threadIdx.x;   // 2*1024*512
    int c  = idx & 511;
    int bl = idx >> 9;
    int b = bl >> 10, l = bl & 1023;
    int r, col;
    if (c < 256) { r = b * 1024 + l;                 col = c; }
    else         { r = 2048 + b * 1024 + (1023 - l); col = c - 256; }
    size_t o = (size_t)r * 256 + col;
    out[idx] = P[o] + P[(size_t)RTOT * 256 + o];
}

// ---------------------------------------------------------------------------
// Depthwise causal conv (K=4) + bias + silu, float4 over channels.
// ---------------------------------------------------------------------------
__global__ __launch_bounds__(256) void conv_silu(
    const float* __restrict__ XZ, const float* __restrict__ cw,
    const float* __restrict__ cb, float* __restrict__ XC, int step)
{
    int n = blockIdx.x * 256 + threadIdx.x;   // RTOT*128 total
    int d4 = n & 127;
    int r  = n >> 7;
    int g = r >> 11, l = r & 1023;
    int lay = g * 2 + step;
    int d = d4 * 4;
    const float* wb = cw + ((size_t)lay * 512 + d) * 4;
    float4 w0 = *(const float4*)&wb[0];
    float4 w1 = *(const float4*)&wb[4];
    float4 w2 = *(const float4*)&wb[8];
    float4 w3 = *(const float4*)&wb[12];
    float4 acc = *(const float4*)&cb[(size_t)lay * 512 + d];
    #pragma unroll
    for (int k = 0; k < 4; k++) {
        int ls = l - 3 + k;
        if (ls < 0) continue;
        float4 xv = *(const float4*)&XZ[(size_t)(r - 3 + k) * 1024 + d];
        float wk0 = (&w0.x)[k], wk1 = (&w1.x)[k], wk2 = (&w2.x)[k], wk3 = (&w3.x)[k];
        acc.x += wk0 * xv.x; acc.y += wk1 * xv.y;
        acc.z += wk2 * xv.z; acc.w += wk3 * xv.w;
    }
    acc.x = silu_f(acc.x); acc.y = silu_f(acc.y);
    acc.z = silu_f(acc.z); acc.w = silu_f(acc.w);
    *(float4*)&XC[(size_t)r * 512 + d] = acc;
}

// ---------------------------------------------------------------------------
// Stage dbl chunk (summing the SKX x_proj slabs) into LDS.
// ---------------------------------------------------------------------------
__device__ __forceinline__ void stage_dbl(
    float dbl[CL][48], const float* __restrict__ Pdbl, int r0, int tid)
{
    for (int id = tid; id < CL * 48; id += 512) {
        int rr = id / 48, cc = id - rr * 48;
        size_t o = (size_t)(r0 + rr) * 48 + cc;
        float v = 0.f;
        #pragma unroll
        for (int s = 0; s < SKX; s++) v += Pdbl[(size_t)s * (RTOT * 48) + o];
        dbl[rr][cc] = v;
    }
}

// ---------------------------------------------------------------------------
// Scan phase A (dt_proj + slab-combine fused): per (gb,chunk,d) -> prod(dA),
// h_end with h0=0.
// ---------------------------------------------------------------------------
__global__ __launch_bounds__(512) void scanA(
    const float* __restrict__ XCb, const float* __restrict__ Pdbl,
    const float* __restrict__ A_log, const float* __restrict__ Wdt,
    const float* __restrict__ bdt,
    float* __restrict__ Aprod, float* __restrict__ Hend, int step)
{
    __shared__ float dbl[CL][48];
    int blk = blockIdx.x;           // gb*CH + c
    int c  = blk & (CH - 1);
    int gb = blk >> 6;
    int g  = gb >> 1;
    int lay = g * 2 + step;
    int d = threadIdx.x;
    int r0 = gb * L + c * CL;

    stage_dbl(dbl, Pdbl, r0, threadIdx.x);

    float wdt[16];
    const float* wrow = Wdt + ((size_t)lay * DI + d) * DR;
    #pragma unroll
    for (int k = 0; k < 16; k += 4) {
        float4 v = *(const float4*)&wrow[k];
        wdt[k] = v.x; wdt[k + 1] = v.y; wdt[k + 2] = v.z; wdt[k + 3] = v.w;
    }
    float bias = bdt[(size_t)lay * DI + d];

    float a[DS], h[DS], ap[DS];
    const float* al = A_log + ((size_t)lay * DI + d) * DS;
    #pragma unroll
    for (int s = 0; s < DS; s++) { a[s] = -__expf(al[s]); h[s] = 0.f; ap[s] = 1.f; }
    __syncthreads();

    for (int tt = 0; tt < CL; tt++) {
        float dtr = bias;
        #pragma unroll
        for (int k = 0; k < 16; k++) dtr += dbl[tt][k] * wdt[k];
        float dt = (dtr > 20.f) ? dtr : log1pf(__expf(dtr));
        float xc = XCb[(size_t)(r0 + tt) * DI + d];
        float dx = dt * xc;
        #pragma unroll
        for (int s = 0; s < DS; s++) {
            float da = __expf(dt * a[s]);
            h[s] = da * h[s] + dx * dbl[tt][16 + s];
            ap[s] *= da;
        }
    }
    size_t base = ((size_t)(gb * DI + d) * CH + c) * DS;
    #pragma unroll
    for (int q = 0; q < 4; q++) {
        *(float4*)&Aprod[base + q * 4] = make_float4(ap[q*4], ap[q*4+1], ap[q*4+2], ap[q*4+3]);
        *(float4*)&Hend [base + q * 4] = make_float4(h[q*4],  h[q*4+1],  h[q*4+2],  h[q*4+3]);
    }
}

// ---------------------------------------------------------------------------
// Combine: serial exclusive scan over 64 chunks per (gb,d,s) lane.
// Hend (in) and Hinit (out) are separate buffers so loads batch ahead.
// ---------------------------------------------------------------------------
__global__ __launch_bounds__(256) void scanCombine(
    const float* __restrict__ Aprod, const float* __restrict__ Hend,
    float* __restrict__ Hinit)
{
    int idx = blockIdx.x * 256 + threadIdx.x;  // (gb*DI+d)*DS + s
    int s  = idx & 15;
    int gd = idx >> 4;
    size_t base = (size_t)gd * CH * DS + s;
    float h = 0.f;
    for (int c0 = 0; c0 < CH; c0 += 8) {
        float ap[8], e[8];
        #pragma unroll
        for (int j = 0; j < 8; j++) {
            size_t o = base + (size_t)(c0 + j) * DS;
            ap[j] = Aprod[o]; e[j] = Hend[o];
        }
        #pragma unroll
        for (int j = 0; j < 8; j++) {
            Hinit[base + (size_t)(c0 + j) * DS] = h;
            h = ap[j] * h + e[j];
        }
    }
}

// ---------------------------------------------------------------------------
// Scan phase B: replay with h_init, fuse +xc*D, *silu(z).
// ---------------------------------------------------------------------------
__global__ __launch_bounds__(512) void scanB(
    const float* __restrict__ XCb, const float* __restrict__ Pdbl,
    const float* __restrict__ XZ, const float* __restrict__ A_log,
    const float* __restrict__ Wdt, const float* __restrict__ bdt,
    const float* __restrict__ Dp, const float* __restrict__ Hinit,
    float* __restrict__ Yb, int step)
{
    __shared__ float dbl[CL][48];
    int blk = blockIdx.x;
    int c  = blk & (CH - 1);
    int gb = blk >> 6;
    int g  = gb >> 1;
    int lay = g * 2 + step;
    int d = threadIdx.x;
    int r0 = gb * L + c * CL;

    stage_dbl(dbl, Pdbl, r0, threadIdx.x);

    float wdt[16];
    const float* wrow = Wdt + ((size_t)lay * DI + d) * DR;
    #pragma unroll
    for (int k = 0; k < 16; k += 4) {
        float4 v = *(const float4*)&wrow[k];
        wdt[k] = v.x; wdt[k + 1] = v.y; wdt[k + 2] = v.z; wdt[k + 3] = v.w;
    }
    float bias = bdt[(size_t)lay * DI + d];

    float a[DS], h[DS];
    const float* al = A_log + ((size_t)lay * DI + d) * DS;
    size_t base = ((size_t)(gb * DI + d) * CH + c) * DS;
    #pragma unroll
    for (int s = 0; s < DS; s++) { a[s] = -__expf(al[s]); h[s] = Hinit[base + s]; }
    float Dv = Dp[(size_t)lay * DI + d];
    __syncthreads();

    for (int tt = 0; tt < CL; tt++) {
        int r = r0 + tt;
        float dtr = bias;
        #pragma unroll
        for (int k = 0; k < 16; k++) dtr += dbl[tt][k] * wdt[k];
        float dt = (dtr > 20.f) ? dtr : log1pf(__expf(dtr));
        float xc = XCb[(size_t)r * DI + d];
        float dx = dt * xc;
        float y = 0.f;
        #pragma unroll
        for (int s = 0; s < DS; s++) {
            float da = __expf(dt * a[s]);
            h[s] = da * h[s] + dx * dbl[tt][16 + s];
            y += h[s] * dbl[tt][32 + s];
        }
        y += xc * Dv;
        float z = XZ[(size_t)r * 1024 + 512 + d];
        y *= silu_f(z);
        Yb[(size_t)r * DI + d] = y;
    }
}

extern "C" void kernel_launch(void* const* d_in, const int* in_sizes, int n_in,
                              void* d_out, int out_size, void* d_ws, size_t ws_size,
                              hipStream_t stream)
{
    const float* x        = (const float*)d_in[0];
    const float* in_proj  = (const float*)d_in[1];
    const float* conv_w   = (const float*)d_in[2];
    const float* conv_b   = (const float*)d_in[3];
    const float* x_proj   = (const float*)d_in[4];
    const float* dt_proj  = (const float*)d_in[5];
    const float* dt_bias  = (const float*)d_in[6];
    const float* A_log    = (const float*)d_in[7];
    const float* Dp       = (const float*)d_in[8];
    const float* out_proj = (const float*)d_in[9];
    float* out = (float*)d_out;

    float* w = (float*)d_ws;
    size_t o = 0;
    float* XZ    = w + o; o += (size_t)RTOT * 1024;            // 16.8MB
    float* XCb   = w + o; o += (size_t)RTOT * DI;              // 8.4MB
    float* Yb    = w + o; o += (size_t)RTOT * DI;              // 8.4MB
    float* Pdbl  = w + o; o += (size_t)SKX * RTOT * 48;        // 6.3MB
    float* Aprod = w + o; o += (size_t)G * BB * DI * CH * DS;  // 2.1MB
    float* Hend  = w + o; o += (size_t)G * BB * DI * CH * DS;  // 2.1MB
    float* Hinit = w + o; o += (size_t)G * BB * DI * CH * DS;  // 2.1MB
    float* Pout  = w + o; o += (size_t)2 * RTOT * DM;          // 8.4MB
    (void)ws_size; (void)in_sizes; (void)n_in; (void)out_size;

    for (int step = 0; step < 2; step++) {
        // in_proj: 4096x1024, K=256. 64x64 tiles -> 1024 blocks.
        if (step == 0)
            gemm64<1, 1><<<dim3(16, 64, 1), 256, 0, stream>>>(
                x, 0, DM, DM, in_proj, 2 * DI, 0, XZ, 1024, 0);
        else
            gemm64<1, 2><<<dim3(16, 64, 1), 256, 0, stream>>>(
                Pout, (size_t)RTOT * DM, DM, DM, in_proj, 2 * DI, 1, XZ, 1024, 0);
        conv_silu<<<RTOT * 128 / 256, 256, 0, stream>>>(XZ, conv_w, conv_b, XCb, step);
        // x_proj: 4096x48, K=512 split-8 -> 512 blocks, private slabs.
        gemm64<SKX, 0><<<dim3(1, 64, SKX), 256, 0, stream>>>(
            XCb, 0, DI, DI, x_proj, 48, step, Pdbl, 48, (size_t)RTOT * 48);
        // fused dt_proj + slab combine + chunked scan
        scanA<<<G * BB * CH, 512, 0, stream>>>(
            XCb, Pdbl, A_log, dt_proj, dt_bias, Aprod, Hend, step);
        scanCombine<<<(G * BB * DI * DS) / 256, 256, 0, stream>>>(Aprod, Hend, Hinit);
        scanB<<<G * BB * CH, 512, 0, stream>>>(
            XCb, Pdbl, XZ, A_log, dt_proj, dt_bias, Dp, Hinit, Yb, step);
        // out_proj: 4096x256, K=512 split-2 -> 512 blocks, private slabs.
        gemm64<2, 0><<<dim3(4, 64, 2), 256, 0, stream>>>(
            Yb, 0, DI, DI, out_proj, DM, step, Pout, DM, (size_t)RTOT * DM);
    }
    combineOut<<<(2 * 1024 * 512) / 256, 256, 0, stream>>>(Pout, out);
}

// Round 6
// 270.186 us; speedup vs baseline: 2.0207x; 1.2359x over previous
//
#include <hip/hip_runtime.h>
#include <math.h>

#define G 2
#define BB 2
#define L 1024
#define DM 256
#define DI 512
#define DS 16
#define DR 16
#define CH 64
#define CL 16              // L / CH
#define RTOT (G*BB*L)      // 4096 rows per layer-step
#define SKX 8              // x_proj split-K factor

typedef short bh8 __attribute__((ext_vector_type(8)));
typedef float f4x __attribute__((ext_vector_type(4)));

__device__ __forceinline__ float silu_f(float x) { return x / (1.f + __expf(-x)); }

__device__ __forceinline__ unsigned short f2bf(float f) {
    unsigned u = __float_as_uint(f);
    unsigned r = u + 0x7FFFu + ((u >> 16) & 1u);
    return (unsigned short)(r >> 16);
}
__device__ __forceinline__ float bf2f(unsigned short s) {
    return __uint_as_float(((unsigned)s) << 16);
}

// ---------------------------------------------------------------------------
// MFMA GEMM via 3xbf16 splitting (fp32-grade accuracy on the matrix pipe).
// C[z][r][n] = sum_k A[r][k] * W[lay][n][k]; lay = (row0>>11)*2 + step.
// BN=64 fixed; BM in {64,128}; BK=32. 256 threads = 4 waves; wave computes
// (BM/2) x 32 via 16x16x32 bf16 MFMAs, 3 per position (hh, hl, lh).
// AMAP 0: A direct. AMAP 1: A = x, g-dependent time reversal (step0 in_proj).
// AMAP 2: A = slab0+slab1 of Pout (fuses out_proj combine into step1 in_proj).
// Split-K blocks write private slabs (z*partStride). No atomics.
// ---------------------------------------------------------------------------
template<int BM, int SPLITK, int AMAP>
__global__ __launch_bounds__(256) void mfma_gemm(
    const float* __restrict__ A, size_t slabOff, int lda, int Ktot,
    const float* __restrict__ W, int Nout, int step,
    float* __restrict__ C, int ldc, size_t partStride)
{
    constexpr int AP = BM / 32;          // A positions per wave (16-row units)
    constexpr int CA = BM / 32;          // A float4-chunks staged per thread
    __shared__ short As_hi[BM * 40];
    __shared__ short As_lo[BM * 40];
    __shared__ short Bs_hi[64 * 40];
    __shared__ short Bs_lo[64 * 40];

    const int row0 = blockIdx.y * BM;
    const int col0 = blockIdx.x * 64;
    const int g    = row0 >> 11;
    const int lay  = g * 2 + step;
    const float* Wg = W + (size_t)lay * Nout * Ktot;
    const int t    = threadIdx.x;
    const int lane = t & 63, wv = t >> 6;
    const int m = lane & 15, quad = lane >> 4;
    const int wr = wv >> 1, wc = wv & 1;

    const int Kc    = Ktot / SPLITK;
    const int kbase = blockIdx.z * Kc;
    const int NT    = Kc / 32;

    float4 pa[CA], pa2[CA], pb[2];
    auto loadT = [&](int kt) {
        const int kb = kbase + kt * 32;
        #pragma unroll
        for (int i = 0; i < CA; i++) {
            int id = t + 256 * i;
            int row = id >> 3, kq = id & 7;
            size_t arow;
            if (AMAP == 1) {
                int gr = row0 + row;
                int gg = gr >> 11, b = (gr >> 10) & 1, l = gr & 1023;
                int sl = gg ? (1023 - l) : l;
                arow = (size_t)(b * 1024 + sl);
            } else {
                arow = (size_t)(row0 + row);
            }
            pa[i] = *(const float4*)&A[arow * lda + kb + kq * 4];
            if (AMAP == 2)
                pa2[i] = *(const float4*)&A[slabOff + arow * lda + kb + kq * 4];
        }
        #pragma unroll
        for (int i = 0; i < 2; i++) {
            int id = t + 256 * i;
            int row = id >> 3, kq = id & 7;
            pb[i] = *(const float4*)&Wg[(size_t)(col0 + row) * Ktot + kb + kq * 4];
        }
    };
    auto cvt_store = [&](short* hi, short* lo, int row, int kq, float4 v) {
        short4 h, l;
        unsigned short s;
        s = f2bf(v.x); h.x = (short)s; l.x = (short)f2bf(v.x - bf2f(s));
        s = f2bf(v.y); h.y = (short)s; l.y = (short)f2bf(v.y - bf2f(s));
        s = f2bf(v.z); h.z = (short)s; l.z = (short)f2bf(v.z - bf2f(s));
        s = f2bf(v.w); h.w = (short)s; l.w = (short)f2bf(v.w - bf2f(s));
        *(short4*)&hi[row * 40 + kq * 4] = h;
        *(short4*)&lo[row * 40 + kq * 4] = l;
    };

    f4x acc[AP][2] = {};
    loadT(0);

    for (int kt = 0; kt < NT; kt++) {
        #pragma unroll
        for (int i = 0; i < CA; i++) {
            int id = t + 256 * i;
            int row = id >> 3, kq = id & 7;
            float4 v = pa[i];
            if (AMAP == 2) { v.x += pa2[i].x; v.y += pa2[i].y; v.z += pa2[i].z; v.w += pa2[i].w; }
            cvt_store(As_hi, As_lo, row, kq, v);
        }
        #pragma unroll
        for (int i = 0; i < 2; i++) {
            int id = t + 256 * i;
            int row = id >> 3, kq = id & 7;
            cvt_store(Bs_hi, Bs_lo, row, kq, pb[i]);
        }
        __syncthreads();
        if (kt + 1 < NT) loadT(kt + 1);

        bh8 ah[AP], al[AP], bh[2], bl[2];
        #pragma unroll
        for (int p = 0; p < AP; p++) {
            int r = wr * (BM / 2) + p * 16 + m;
            ah[p] = *(bh8*)&As_hi[r * 40 + quad * 8];
            al[p] = *(bh8*)&As_lo[r * 40 + quad * 8];
        }
        #pragma unroll
        for (int pb_ = 0; pb_ < 2; pb_++) {
            int r = wc * 32 + pb_ * 16 + m;
            bh[pb_] = *(bh8*)&Bs_hi[r * 40 + quad * 8];
            bl[pb_] = *(bh8*)&Bs_lo[r * 40 + quad * 8];
        }
        #pragma unroll
        for (int p = 0; p < AP; p++)
            #pragma unroll
            for (int q = 0; q < 2; q++) {
                acc[p][q] = __builtin_amdgcn_mfma_f32_16x16x32_bf16(ah[p], bh[q], acc[p][q], 0, 0, 0);
                acc[p][q] = __builtin_amdgcn_mfma_f32_16x16x32_bf16(ah[p], bl[q], acc[p][q], 0, 0, 0);
                acc[p][q] = __builtin_amdgcn_mfma_f32_16x16x32_bf16(al[p], bh[q], acc[p][q], 0, 0, 0);
            }
        __syncthreads();
    }

    float* Cz = C + (size_t)blockIdx.z * partStride;
    #pragma unroll
    for (int p = 0; p < AP; p++)
        #pragma unroll
        for (int q = 0; q < 2; q++) {
            int gcol = col0 + wc * 32 + q * 16 + m;
            #pragma unroll
            for (int r = 0; r < 4; r++) {
                int grow = row0 + wr * (BM / 2) + p * 16 + quad * 4 + r;
                Cz[(size_t)grow * ldc + gcol] = acc[p][q][r];
            }
        }
}

// ---------------------------------------------------------------------------
// fp32 GEMM, 64x64 tile, 4x4 microtile (kept for x_proj, N=48).
// ---------------------------------------------------------------------------
template<int SPLITK>
__global__ __launch_bounds__(256) void gemm64(
    const float* __restrict__ A, int lda, int Ktot,
    const float* __restrict__ W, int Nout, int step,
    float* __restrict__ C, int ldc, size_t partStride)
{
    __shared__ float As[16][68];
    __shared__ float Bs[16][68];

    const int row0 = blockIdx.y * 64;
    const int col0 = blockIdx.x * 64;
    const int g    = row0 >> 11;
    const int lay  = g * 2 + step;
    const float* Wg = W + (size_t)lay * Nout * Ktot;
    const int t  = threadIdx.x;
    const int tx = t & 15, ty = t >> 4;
    const int Kc    = Ktot / SPLITK;
    const int kbase = blockIdx.z * Kc;
    const int NT    = Kc / 16;

    const int sr = t >> 2;
    const int sk = (t & 3) * 4;
    const size_t arow = (size_t)(row0 + sr);
    const bool bok = (col0 + sr < Nout);

    float4 pa, pb;
    auto loadT = [&](int kt) {
        const int kb = kbase + kt * 16 + sk;
        pa = *(const float4*)&A[arow * lda + kb];
        pb = bok ? *(const float4*)&Wg[(size_t)(col0 + sr) * Ktot + kb]
                 : make_float4(0.f, 0.f, 0.f, 0.f);
    };

    float acc[4][4] = {};
    loadT(0);

    for (int kt = 0; kt < NT; kt++) {
        As[sk + 0][sr] = pa.x; As[sk + 1][sr] = pa.y;
        As[sk + 2][sr] = pa.z; As[sk + 3][sr] = pa.w;
        Bs[sk + 0][sr] = pb.x; Bs[sk + 1][sr] = pb.y;
        Bs[sk + 2][sr] = pb.z; Bs[sk + 3][sr] = pb.w;
        __syncthreads();
        if (kt + 1 < NT) loadT(kt + 1);
        #pragma unroll
        for (int kk = 0; kk < 16; kk++) {
            float4 a = *(const float4*)&As[kk][ty * 4];
            float4 b = *(const float4*)&Bs[kk][tx * 4];
            float av[4] = {a.x, a.y, a.z, a.w};
            float bv[4] = {b.x, b.y, b.z, b.w};
            #pragma unroll
            for (int i = 0; i < 4; i++)
                #pragma unroll
                for (int j = 0; j < 4; j++) acc[i][j] += av[i] * bv[j];
        }
        __syncthreads();
    }

    float* Cz = C + (size_t)blockIdx.z * partStride;
    const int col = col0 + tx * 4;
    if (col < Nout) {
        #pragma unroll
        for (int i = 0; i < 4; i++) {
            int r = row0 + ty * 4 + i;
            *(float4*)&Cz[(size_t)r * ldc + col] =
                make_float4(acc[i][0], acc[i][1], acc[i][2], acc[i][3]);
        }
    }
}

// ---------------------------------------------------------------------------
// Final out_proj combine (2 slabs) + time-reversal scatter into d_out.
// ---------------------------------------------------------------------------
__global__ __launch_bounds__(256) void combineOut(
    const float* __restrict__ P, float* __restrict__ out)
{
    int idx = blockIdx.x * 256 + threadIdx.x;   // 2*1024*512
    int c  = idx & 511;
    int bl = idx >> 9;
    int b = bl >> 10, l = bl & 1023;
    int r, col;
    if (c < 256) { r = b * 1024 + l;                 col = c; }
    else         { r = 2048 + b * 1024 + (1023 - l); col = c - 256; }
    size_t o = (size_t)r * 256 + col;
    out[idx] = P[o] + P[(size_t)RTOT * 256 + o];
}

// ---------------------------------------------------------------------------
// Depthwise causal conv (K=4) + bias + silu, float4 over channels.
// ---------------------------------------------------------------------------
__global__ __launch_bounds__(256) void conv_silu(
    const float* __restrict__ XZ, const float* __restrict__ cw,
    const float* __restrict__ cb, float* __restrict__ XC, int step)
{
    int n = blockIdx.x * 256 + threadIdx.x;   // RTOT*128 total
    int d4 = n & 127;
    int r  = n >> 7;
    int g = r >> 11, l = r & 1023;
    int lay = g * 2 + step;
    int d = d4 * 4;
    const float* wb = cw + ((size_t)lay * 512 + d) * 4;
    float4 w0 = *(const float4*)&wb[0];
    float4 w1 = *(const float4*)&wb[4];
    float4 w2 = *(const float4*)&wb[8];
    float4 w3 = *(const float4*)&wb[12];
    float4 acc = *(const float4*)&cb[(size_t)lay * 512 + d];
    #pragma unroll
    for (int k = 0; k < 4; k++) {
        int ls = l - 3 + k;
        if (ls < 0) continue;
        float4 xv = *(const float4*)&XZ[(size_t)(r - 3 + k) * 1024 + d];
        float wk0 = (&w0.x)[k], wk1 = (&w1.x)[k], wk2 = (&w2.x)[k], wk3 = (&w3.x)[k];
        acc.x += wk0 * xv.x; acc.y += wk1 * xv.y;
        acc.z += wk2 * xv.z; acc.w += wk3 * xv.w;
    }
    acc.x = silu_f(acc.x); acc.y = silu_f(acc.y);
    acc.z = silu_f(acc.z); acc.w = silu_f(acc.w);
    *(float4*)&XC[(size_t)r * 512 + d] = acc;
}

// ---------------------------------------------------------------------------
// Stage dbl chunk (summing the SKX x_proj slabs) into LDS.
// ---------------------------------------------------------------------------
__device__ __forceinline__ void stage_dbl(
    float dbl[CL][48], const float* __restrict__ Pdbl, int r0, int tid)
{
    for (int id = tid; id < CL * 48; id += 512) {
        int rr = id / 48, cc = id - rr * 48;
        size_t o = (size_t)(r0 + rr) * 48 + cc;
        float v = 0.f;
        #pragma unroll
        for (int s = 0; s < SKX; s++) v += Pdbl[(size_t)s * (RTOT * 48) + o];
        dbl[rr][cc] = v;
    }
}

// ---------------------------------------------------------------------------
// Scan phase A (dt_proj + slab-combine fused): per (gb,chunk,d) -> prod(dA),
// h_end with h0=0.
// ---------------------------------------------------------------------------
__global__ __launch_bounds__(512) void scanA(
    const float* __restrict__ XCb, const float* __restrict__ Pdbl,
    const float* __restrict__ A_log, const float* __restrict__ Wdt,
    const float* __restrict__ bdt,
    float* __restrict__ Aprod, float* __restrict__ Hend, int step)
{
    __shared__ float dbl[CL][48];
    int blk = blockIdx.x;           // gb*CH + c
    int c  = blk & (CH - 1);
    int gb = blk >> 6;
    int g  = gb >> 1;
    int lay = g * 2 + step;
    int d = threadIdx.x;
    int r0 = gb * L + c * CL;

    stage_dbl(dbl, Pdbl, r0, threadIdx.x);

    float wdt[16];
    const float* wrow = Wdt + ((size_t)lay * DI + d) * DR;
    #pragma unroll
    for (int k = 0; k < 16; k += 4) {
        float4 v = *(const float4*)&wrow[k];
        wdt[k] = v.x; wdt[k + 1] = v.y; wdt[k + 2] = v.z; wdt[k + 3] = v.w;
    }
    float bias = bdt[(size_t)lay * DI + d];

    float a[DS], h[DS], ap[DS];
    const float* al = A_log + ((size_t)lay * DI + d) * DS;
    #pragma unroll
    for (int s = 0; s < DS; s++) { a[s] = -__expf(al[s]); h[s] = 0.f; ap[s] = 1.f; }
    __syncthreads();

    for (int tt = 0; tt < CL; tt++) {
        float dtr = bias;
        #pragma unroll
        for (int k = 0; k < 16; k++) dtr += dbl[tt][k] * wdt[k];
        float dt = (dtr > 20.f) ? dtr : log1pf(__expf(dtr));
        float xc = XCb[(size_t)(r0 + tt) * DI + d];
        float dx = dt * xc;
        #pragma unroll
        for (int s = 0; s < DS; s++) {
            float da = __expf(dt * a[s]);
            h[s] = da * h[s] + dx * dbl[tt][16 + s];
            ap[s] *= da;
        }
    }
    size_t base = ((size_t)(gb * DI + d) * CH + c) * DS;
    #pragma unroll
    for (int q = 0; q < 4; q++) {
        *(float4*)&Aprod[base + q * 4] = make_float4(ap[q*4], ap[q*4+1], ap[q*4+2], ap[q*4+3]);
        *(float4*)&Hend [base + q * 4] = make_float4(h[q*4],  h[q*4+1],  h[q*4+2],  h[q*4+3]);
    }
}

// ---------------------------------------------------------------------------
// Combine: serial exclusive scan over 64 chunks per (gb,d,s) lane.
// ---------------------------------------------------------------------------
__global__ __launch_bounds__(256) void scanCombine(
    const float* __restrict__ Aprod, const float* __restrict__ Hend,
    float* __restrict__ Hinit)
{
    int idx = blockIdx.x * 256 + threadIdx.x;  // (gb*DI+d)*DS + s
    int s  = idx & 15;
    int gd = idx >> 4;
    size_t base = (size_t)gd * CH * DS + s;
    float h = 0.f;
    for (int c0 = 0; c0 < CH; c0 += 8) {
        float ap[8], e[8];
        #pragma unroll
        for (int j = 0; j < 8; j++) {
            size_t o = base + (size_t)(c0 + j) * DS;
            ap[j] = Aprod[o]; e[j] = Hend[o];
        }
        #pragma unroll
        for (int j = 0; j < 8; j++) {
            Hinit[base + (size_t)(c0 + j) * DS] = h;
            h = ap[j] * h + e[j];
        }
    }
}

// ---------------------------------------------------------------------------
// Scan phase B: replay with h_init, fuse +xc*D, *silu(z).
// ---------------------------------------------------------------------------
__global__ __launch_bounds__(512) void scanB(
    const float* __restrict__ XCb, const float* __restrict__ Pdbl,
    const float* __restrict__ XZ, const float* __restrict__ A_log,
    const float* __restrict__ Wdt, const float* __restrict__ bdt,
    const float* __restrict__ Dp, const float* __restrict__ Hinit,
    float* __restrict__ Yb, int step)
{
    __shared__ float dbl[CL][48];
    int blk = blockIdx.x;
    int c  = blk & (CH - 1);
    int gb = blk >> 6;
    int g  = gb >> 1;
    int lay = g * 2 + step;
    int d = threadIdx.x;
    int r0 = gb * L + c * CL;

    stage_dbl(dbl, Pdbl, r0, threadIdx.x);

    float wdt[16];
    const float* wrow = Wdt + ((size_t)lay * DI + d) * DR;
    #pragma unroll
    for (int k = 0; k < 16; k += 4) {
        float4 v = *(const float4*)&wrow[k];
        wdt[k] = v.x; wdt[k + 1] = v.y; wdt[k + 2] = v.z; wdt[k + 3] = v.w;
    }
    float bias = bdt[(size_t)lay * DI + d];

    float a[DS], h[DS];
    const float* al = A_log + ((size_t)lay * DI + d) * DS;
    size_t base = ((size_t)(gb * DI + d) * CH + c) * DS;
    #pragma unroll
    for (int s = 0; s < DS; s++) { a[s] = -__expf(al[s]); h[s] = Hinit[base + s]; }
    float Dv = Dp[(size_t)lay * DI + d];
    __syncthreads();

    for (int tt = 0; tt < CL; tt++) {
        int r = r0 + tt;
        float dtr = bias;
        #pragma unroll
        for (int k = 0; k < 16; k++) dtr += dbl[tt][k] * wdt[k];
        float dt = (dtr > 20.f) ? dtr : log1pf(__expf(dtr));
        float xc = XCb[(size_t)r * DI + d];
        float dx = dt * xc;
        float y = 0.f;
        #pragma unroll
        for (int s = 0; s < DS; s++) {
            float da = __expf(dt * a[s]);
            h[s] = da * h[s] + dx * dbl[tt][16 + s];
            y += h[s] * dbl[tt][32 + s];
        }
        y += xc * Dv;
        float z = XZ[(size_t)r * 1024 + 512 + d];
        y *= silu_f(z);
        Yb[(size_t)r * DI + d] = y;
    }
}

extern "C" void kernel_launch(void* const* d_in, const int* in_sizes, int n_in,
                              void* d_out, int out_size, void* d_ws, size_t ws_size,
                              hipStream_t stream)
{
    const float* x        = (const float*)d_in[0];
    const float* in_proj  = (const float*)d_in[1];
    const float* conv_w   = (const float*)d_in[2];
    const float* conv_b   = (const float*)d_in[3];
    const float* x_proj   = (const float*)d_in[4];
    const float* dt_proj  = (const float*)d_in[5];
    const float* dt_bias  = (const float*)d_in[6];
    const float* A_log    = (const float*)d_in[7];
    const float* Dp       = (const float*)d_in[8];
    const float* out_proj = (const float*)d_in[9];
    float* out = (float*)d_out;

    float* w = (float*)d_ws;
    size_t o = 0;
    float* XZ    = w + o; o += (size_t)RTOT * 1024;
    float* XCb   = w + o; o += (size_t)RTOT * DI;
    float* Yb    = w + o; o += (size_t)RTOT * DI;
    float* Pdbl  = w + o; o += (size_t)SKX * RTOT * 48;
    float* Aprod = w + o; o += (size_t)G * BB * DI * CH * DS;
    float* Hend  = w + o; o += (size_t)G * BB * DI * CH * DS;
    float* Hinit = w + o; o += (size_t)G * BB * DI * CH * DS;
    float* Pout  = w + o; o += (size_t)2 * RTOT * DM;
    (void)ws_size; (void)in_sizes; (void)n_in; (void)out_size;

    for (int step = 0; step < 2; step++) {
        // in_proj: 4096x1024, K=256, MFMA 3xbf16. 128x64 tiles -> 512 blocks.
        if (step == 0)
            mfma_gemm<128, 1, 1><<<dim3(16, 32, 1), 256, 0, stream>>>(
                x, 0, DM, DM, in_proj, 2 * DI, 0, XZ, 1024, 0);
        else
            mfma_gemm<128, 1, 2><<<dim3(16, 32, 1), 256, 0, stream>>>(
                Pout, (size_t)RTOT * DM, DM, DM, in_proj, 2 * DI, 1, XZ, 1024, 0);
        conv_silu<<<RTOT * 128 / 256, 256, 0, stream>>>(XZ, conv_w, conv_b, XCb, step);
        // x_proj: 4096x48, K=512 split-8 -> 512 blocks, fp32, private slabs.
        gemm64<SKX><<<dim3(1, 64, SKX), 256, 0, stream>>>(
            XCb, DI, DI, x_proj, 48, step, Pdbl, 48, (size_t)RTOT * 48);
        // fused dt_proj + slab combine + chunked scan
        scanA<<<G * BB * CH, 512, 0, stream>>>(
            XCb, Pdbl, A_log, dt_proj, dt_bias, Aprod, Hend, step);
        scanCombine<<<(G * BB * DI * DS) / 256, 256, 0, stream>>>(Aprod, Hend, Hinit);
        scanB<<<G * BB * CH, 512, 0, stream>>>(
            XCb, Pdbl, XZ, A_log, dt_proj, dt_bias, Dp, Hinit, Yb, step);
        // out_proj: 4096x256, K=512, MFMA 3xbf16, split-2 -> 512 blocks.
        mfma_gemm<64, 2, 0><<<dim3(4, 64, 2), 256, 0, stream>>>(
            Yb, 0, DI, DI, out_proj, DM, step, Pout, DM, (size_t)RTOT * DM);
    }
    combineOut<<<(2 * 1024 * 512) / 256, 256, 0, stream>>>(Pout, out);
}